// Round 4
// baseline (309.767 us; speedup 1.0000x reference)
//
#include <hip/hip_runtime.h>

// LCN: B=512, C=1, H=W=280, K=S=28, F=10, SPAN=100 (10x10), DEC_IN=1000, OUT=10
#define HW     280
#define IMG    78400          // 280*280
#define KK     28
#define F_N    10
#define SPAN   100
#define OUT_N  10
#define XSTR   282            // LDS batch stride in floats: 8B-aligned, 26*lane%32 -> ~2-way banks (free)
#define P_RQ   512000         // P plane stride: 1000*512

// Conv: grid 320 = rq(4) x hs(10) x bg(8); block 256 = 4 waves; ALL ws per block.
// Staging reads FULL 1120B image rows (perfectly coalesced, x read exactly once);
// compute: lane = batch -> w index wave-uniform -> s_load from scalar cache;
// x served from LDS. Wave wid owns 5 ws x 5 f = 25 accumulators.
__global__ __launch_bounds__(256, 1) void lcn_conv(
    const float* __restrict__ x, const float* __restrict__ cw,
    float* __restrict__ P) {
  const int bid = blockIdx.x;          // rq*80 + hs*8 + bg
  const int rq  = bid / 80;
  const int rem = bid - rq * 80;
  const int hs  = rem >> 3;
  const int bg  = rem & 7;

  const int lane = threadIdx.x & 63;
  const int swid = __builtin_amdgcn_readfirstlane((int)(threadIdx.x >> 6));
  const int ws0  = (swid & 1) * 5;     // wave's ws half
  const int f0   = (swid >> 1) * 5;    // wave's f half

  __shared__ float xb[64 * XSTR];      // 72192 B -> 2 blocks/CU

  const float* xbase = x + (size_t)bg * (64 * IMG)
                         + (size_t)(hs * KK + rq * 7) * HW;

  float acc[5][5];
#pragma unroll
  for (int i = 0; i < 5; ++i)
#pragma unroll
    for (int j = 0; j < 5; ++j) acc[i][j] = 0.f;

  float4 stg[18];                      // reg-staged row (T14 split)

  auto load_row = [&](int k) {         // issue global loads: 64 b x 70 float4
#pragma unroll
    for (int j = 0; j < 18; ++j) {
      const int i = (int)threadIdx.x + 256 * j;
      if (i < 4480) {
        const int b = i / 70, q = i - b * 70;
        stg[j] = *reinterpret_cast<const float4*>(
            xbase + (size_t)b * IMG + k * HW + q * 4);
      }
    }
  };
  auto write_row = [&]() {             // LDS write at padded stride (8B granules)
#pragma unroll
    for (int j = 0; j < 18; ++j) {
      const int i = (int)threadIdx.x + 256 * j;
      if (i < 4480) {
        const int b = i / 70, q = i - b * 70;
        float2* dst = reinterpret_cast<float2*>(&xb[b * XSTR + q * 4]);
        dst[0] = make_float2(stg[j].x, stg[j].y);
        dst[1] = make_float2(stg[j].z, stg[j].w);
      }
    }
  };

  load_row(0);
  write_row();
  __syncthreads();

  for (int k = 0; k < 7; ++k) {
    if (k < 6) load_row(k + 1);        // in flight under compute

    const int prow = rq * 7 + k;       // patch-row index (w row)
    const float* xr = &xb[lane * XSTR];
#pragma unroll
    for (int wsi = 0; wsi < 5; ++wsi) {
      const int ws = ws0 + wsi;
      float2 xv[14];
#pragma unroll
      for (int c = 0; c < 14; ++c)
        xv[c] = *reinterpret_cast<const float2*>(&xr[ws * KK + c * 2]);
      const int s = hs * 10 + ws;
#pragma unroll
      for (int fi = 0; fi < 5; ++fi) {
        const float* wr = cw + (size_t)((f0 + fi) * SPAN + s) * (KK * KK)
                             + prow * KK;     // wave-uniform -> s_load
#pragma unroll
        for (int c = 0; c < 14; ++c) {
          const float2 wv = *reinterpret_cast<const float2*>(wr + c * 2);
          acc[wsi][fi] = fmaf(xv[c].x, wv.x, acc[wsi][fi]);
          acc[wsi][fi] = fmaf(xv[c].y, wv.y, acc[wsi][fi]);
        }
      }
    }

    if (k < 6) {
      __syncthreads();                 // everyone done reading xb
      write_row();                     // vmcnt drains, ds_write row k+1
      __syncthreads();                 // xb ready
    }
  }

  // partials: P[rq][f*100+s][b], each slot written exactly once, coalesced over b
  float* Pp = P + (size_t)rq * P_RQ + (size_t)bg * 64 + lane;
#pragma unroll
  for (int wsi = 0; wsi < 5; ++wsi)
#pragma unroll
    for (int fi = 0; fi < 5; ++fi)
      Pp[(size_t)((f0 + fi) * SPAN + hs * 10 + ws0 + wsi) * 512] = acc[wsi][fi];
}

// Combine + decoder: h = relu(sum_rq P + cb), yp[dc*4+wid][o][b] = sum_d h*dw.
// grid 80 = dc(10) x bg(8); wave wid owns 25 d's; lane = b (coalesced).
__global__ __launch_bounds__(256) void lcn_dec(
    const float* __restrict__ P, const float* __restrict__ cb,
    const float* __restrict__ dw, float* __restrict__ yp) {
  const int bid  = blockIdx.x;
  const int dc   = bid >> 3;
  const int bg   = bid & 7;
  const int lane = threadIdx.x & 63;
  const int swid = __builtin_amdgcn_readfirstlane((int)(threadIdx.x >> 6));
  const int dbase = dc * 100 + swid * 25;

  const float* Pb = P + (size_t)bg * 64 + lane;
  float acc[OUT_N];
#pragma unroll
  for (int o = 0; o < OUT_N; ++o) acc[o] = 0.f;

  for (int dd = 0; dd < 25; ++dd) {
    const int d = dbase + dd;                       // wave-uniform
    const float* pd = Pb + (size_t)d * 512;
    float p = pd[0] + pd[P_RQ] + pd[2 * P_RQ] + pd[3 * P_RQ];
    float h = fmaxf(p + cb[d], 0.f);
#pragma unroll
    for (int o = 0; o < OUT_N; ++o)
      acc[o] = fmaf(h, dw[o * 1000 + d], acc[o]);   // s_load
  }
  float* ypp = yp + (size_t)(dc * 4 + swid) * 5120 + bg * 64 + lane;
#pragma unroll
  for (int o = 0; o < OUT_N; ++o)
    ypp[o * 512] = acc[o];
}

// y[b][o] = db[o] + sum over 40 yp planes (coalesced per plane)
__global__ __launch_bounds__(256) void lcn_yred(
    const float* __restrict__ yp, const float* __restrict__ db,
    float* __restrict__ y) {
  const int idx = blockIdx.x * 256 + threadIdx.x;   // 0..5119 = o*512 + b
  const int o = idx / 512;
  const int b = idx - o * 512;
  float a = db[o];
#pragma unroll 8
  for (int p = 0; p < 40; ++p) a += yp[(size_t)p * 5120 + idx];
  y[b * OUT_N + o] = a;
}

extern "C" void kernel_launch(void* const* d_in, const int* in_sizes, int n_in,
                              void* d_out, int out_size, void* d_ws, size_t ws_size,
                              hipStream_t stream) {
  const float* x  = (const float*)d_in[0];   // [512,1,280,280]
  const float* cw = (const float*)d_in[1];   // [1000,1,28,28]
  const float* cb = (const float*)d_in[2];   // [1000,1]
  const float* dw = (const float*)d_in[3];   // [10,1000]
  const float* db = (const float*)d_in[4];   // [10]
  float* y = (float*)d_out;                  // [512,10]

  float* P  = (float*)d_ws;                  // [4][1000][512] = 8.192 MB
  float* yp = P + 4 * P_RQ;                  // [40][10][512]  = 0.819 MB

  lcn_conv<<<dim3(320), dim3(256), 0, stream>>>(x, cw, P);
  lcn_dec <<<dim3(80),  dim3(256), 0, stream>>>(P, cb, dw, yp);
  lcn_yred<<<dim3(20),  dim3(256), 0, stream>>>(yp, db, y);
}

// Round 5
// 46.843 us; speedup vs baseline: 6.6129x; 6.6129x over previous
//
#include <hip/hip_runtime.h>

// LCN: B=512, C=1, H=W=280, K=S=28, F=10, SPAN=100 (10x10), DEC_IN=1000, OUT=10
#define HW      280
#define IMG     78400        // 280*280
#define KK      28
#define F_N     10
#define SPAN    100
#define OUT_N   10
#define NB      4            // batches per thread
#define RQR     14           // patch rows per rq half
#define WQ      (RQR * 7)    // 98 float4 of w per filter per half
#define P_PLANE 512000       // 1000*512

// 8-lane-group reduction: sum over c4 = 0..7. xor1/xor2 via DPP quad_perm
// (VALU pipe, keeps pressure off the LDS pipe), xor4 via ds_swizzle.
__device__ __forceinline__ float red8(float v) {
  v += __int_as_float(__builtin_amdgcn_mov_dpp(__float_as_int(v), 0xB1, 0xF, 0xF, true)); // xor 1
  v += __int_as_float(__builtin_amdgcn_mov_dpp(__float_as_int(v), 0x4E, 0xF, 0xF, true)); // xor 2
  v += __int_as_float(__builtin_amdgcn_ds_swizzle(__float_as_int(v), 0x101F));            // xor 4
  return v;
}

// Conv partials: grid 800 = t(8: rq x bg) x s(100), decode t = bid&7 so each
// XCD owns all 100 s of one (rq,bg) -> ws-neighbor line straddles hit same L2.
// Block 256 = 4 waves x 8 groups x 8 lanes; each 8-lane group handles NB=4
// batches; lane c4 covers one float4 column quad (c4==7 inert in conv, 28=7*4).
// w staged once in LDS (15.7 KB); each ds_read_b128 of w feeds 16 FMAs.
__global__ __launch_bounds__(256) void lcn_conv(
    const float* __restrict__ x, const float* __restrict__ cw,
    float* __restrict__ P) {
  const int bid = blockIdx.x;        // 0..799
  const int t   = bid & 7;
  const int s   = bid >> 3;          // 0..99
  const int rq  = t >> 2;            // row half: rows rq*14 .. rq*14+13
  const int bg  = t & 3;             // 128-batch group
  const int hs  = s / 10, ws = s - hs * 10;

  const int lane = threadIdx.x & 63;
  const int wid  = threadIdx.x >> 6;
  const int c4   = lane & 7;
  const int g    = lane >> 3;
  const int b0   = bg * 128 + wid * 32 + g * 4;

  __shared__ float4 wl[F_N * WQ];    // [f][r*7+c4], 980 float4 = 15.68 KB
  {
    const float4* wg = reinterpret_cast<const float4*>(cw);
    for (int i = (int)threadIdx.x; i < F_N * WQ; i += 256) {
      const int f = i / WQ, rem = i - f * WQ;
      wl[i] = wg[(f * SPAN + s) * 196 + rq * WQ + rem];
    }
  }
  __syncthreads();

  float acc[NB][F_N];
#pragma unroll
  for (int bi = 0; bi < NB; ++bi)
#pragma unroll
    for (int f = 0; f < F_N; ++f) acc[bi][f] = 0.f;

  const float* xb = x + (size_t)(hs * KK + rq * RQR) * HW + ws * KK + c4 * 4;
  const float* xr[NB];
#pragma unroll
  for (int bi = 0; bi < NB; ++bi) xr[bi] = xb + (size_t)(b0 + bi) * IMG;

#define COMPUTE(ROW, XV)                                                  \
  {                                                                       \
    _Pragma("unroll")                                                     \
    for (int f = 0; f < F_N; ++f) {                                       \
      const float4 wv = wl[f * WQ + (ROW) * 7 + c4];                      \
      _Pragma("unroll")                                                   \
      for (int bi = 0; bi < NB; ++bi) {                                   \
        acc[bi][f] = fmaf(XV[bi].x, wv.x, acc[bi][f]);                    \
        acc[bi][f] = fmaf(XV[bi].y, wv.y, acc[bi][f]);                    \
        acc[bi][f] = fmaf(XV[bi].z, wv.z, acc[bi][f]);                    \
        acc[bi][f] = fmaf(XV[bi].w, wv.w, acc[bi][f]);                    \
      }                                                                   \
    }                                                                     \
  }

  if (c4 < 7) {
    float4 xvA[NB], xvB[NB];
#pragma unroll
    for (int bi = 0; bi < NB; ++bi)
      xvA[bi] = *reinterpret_cast<const float4*>(xr[bi]);
    for (int r = 0; r < RQR; r += 2) {          // 1-row-ahead prefetch
#pragma unroll
      for (int bi = 0; bi < NB; ++bi)
        xvB[bi] = *reinterpret_cast<const float4*>(xr[bi] + (size_t)(r + 1) * HW);
      COMPUTE(r, xvA)
      if (r + 2 < RQR) {
#pragma unroll
        for (int bi = 0; bi < NB; ++bi)
          xvA[bi] = *reinterpret_cast<const float4*>(xr[bi] + (size_t)(r + 2) * HW);
      }
      COMPUTE(r + 1, xvB)
    }
  }

  // sum over the 8-lane group's column quads (all lanes end with full sums)
#pragma unroll
  for (int bi = 0; bi < NB; ++bi)
#pragma unroll
    for (int f = 0; f < F_N; ++f) acc[bi][f] = red8(acc[bi][f]);

  // P[rq][f*100+s][b]; lane c4 writes f=c4, lanes 0,1 also f=8,9
  float* Pp = P + (size_t)rq * P_PLANE + (size_t)s * 512 + b0;
#pragma unroll
  for (int f = 0; f < F_N; ++f) {
    if (c4 == f || c4 == f - 8) {
#pragma unroll
      for (int bi = 0; bi < NB; ++bi)
        Pp[(size_t)f * (SPAN * 512) + bi] = acc[bi][f];
    }
  }
}

// Combine rq halves + bias + relu + decoder partials.
// grid 200 = dchunk(25) x bg(8); wave wid owns 10 d's; lane = b (coalesced).
__global__ __launch_bounds__(256) void lcn_dec(
    const float* __restrict__ P, const float* __restrict__ cb,
    const float* __restrict__ dw, float* __restrict__ yp) {
  const int bid    = blockIdx.x;
  const int dchunk = bid >> 3;     // 0..24
  const int bg     = bid & 7;
  const int lane   = threadIdx.x & 63;
  const int swid   = __builtin_amdgcn_readfirstlane((int)(threadIdx.x >> 6));
  const int d0     = dchunk * 40 + swid * 10;

  const float* Pb = P + (size_t)bg * 64 + lane;
  float acc[OUT_N];
#pragma unroll
  for (int o = 0; o < OUT_N; ++o) acc[o] = 0.f;

#pragma unroll
  for (int dd = 0; dd < 10; ++dd) {
    const int d = d0 + dd;                         // wave-uniform
    const float p = Pb[(size_t)d * 512] + Pb[(size_t)d * 512 + P_PLANE];
    const float h = fmaxf(p + cb[d], 0.f);
#pragma unroll
    for (int o = 0; o < OUT_N; ++o)
      acc[o] = fmaf(h, dw[o * 1000 + d], acc[o]);  // wave-uniform -> s_load
  }
  float* ypp = yp + (size_t)(dchunk * 4 + swid) * 5120 + bg * 64 + lane;
#pragma unroll
  for (int o = 0; o < OUT_N; ++o) ypp[(size_t)o * 512] = acc[o];
}

// y[b][o] = db[o] + sum over 100 yp planes (coalesced per plane)
__global__ __launch_bounds__(256) void lcn_yred(
    const float* __restrict__ yp, const float* __restrict__ db,
    float* __restrict__ y) {
  const int idx = blockIdx.x * 256 + (int)threadIdx.x;  // 0..5119 = o*512+b
  const int o = idx >> 9;
  const int b = idx & 511;
  float a = db[o];
#pragma unroll 10
  for (int p = 0; p < 100; ++p) a += yp[(size_t)p * 5120 + idx];
  y[b * OUT_N + o] = a;
}

extern "C" void kernel_launch(void* const* d_in, const int* in_sizes, int n_in,
                              void* d_out, int out_size, void* d_ws, size_t ws_size,
                              hipStream_t stream) {
  const float* x  = (const float*)d_in[0];   // [512,1,280,280]
  const float* cw = (const float*)d_in[1];   // [1000,1,28,28]
  const float* cb = (const float*)d_in[2];   // [1000,1]
  const float* dw = (const float*)d_in[3];   // [10,1000]
  const float* db = (const float*)d_in[4];   // [10]
  float* y = (float*)d_out;                  // [512,10]

  float* P  = (float*)d_ws;                  // [2][1000][512] = 4.096 MB
  float* yp = P + 2 * P_PLANE;               // [100][10][512] = 2.048 MB

  lcn_conv<<<dim3(800), dim3(256), 0, stream>>>(x, cw, P);
  lcn_dec <<<dim3(200), dim3(256), 0, stream>>>(P, cb, dw, yp);
  lcn_yred<<<dim3(20),  dim3(256), 0, stream>>>(yp, db, y);
}

// Round 6
// 45.563 us; speedup vs baseline: 6.7987x; 1.0281x over previous
//
#include <hip/hip_runtime.h>

// LCN: B=512, C=1, H=W=280, K=S=28, F=10, SPAN=100 (10x10), DEC_IN=1000, OUT=10
#define HW      280
#define IMG     78400        // 280*280
#define KK      28
#define F_N     10
#define SPAN    100
#define OUT_N   10
#define NB      4            // batches per thread
#define RQR     7            // patch rows per rq quarter
#define WQ      (RQR * 7)    // 49 float4 of w per filter per quarter
#define P_PLANE 512000       // 1000*512

// 8-lane-group reduction, pure DPP (VALU pipe, zero LDS ops):
// xor1 (quad_perm [1,0,3,2]), xor2 (quad_perm [2,3,0,1]); after those the
// value is quad-uniform, so ROW_HALF_MIRROR (lane i <-> 7-i within each 8)
// completes the 8-lane sum.
__device__ __forceinline__ float red8(float v) {
  v += __int_as_float(__builtin_amdgcn_mov_dpp(__float_as_int(v), 0xB1,  0xF, 0xF, true));
  v += __int_as_float(__builtin_amdgcn_mov_dpp(__float_as_int(v), 0x4E,  0xF, 0xF, true));
  v += __int_as_float(__builtin_amdgcn_mov_dpp(__float_as_int(v), 0x141, 0xF, 0xF, true));
  return v;
}

// Conv partials: grid 1600; decode keeps all 10 ws of one (t,hs) on one XCD
// (ws-neighbor patches share straddled 64B lines -> L2 hits).
// Block 256 = 4 waves x 8 groups x 8 lanes; each 8-lane group handles NB=4
// batches; lane c4 = one float4 column quad (c4==7 inert in conv, 28=7*4).
// w for (s, rq) staged in LDS (7.84 KB); each ds_read_b128 of w feeds 16 FMAs.
// Depth-2 row prefetch (3 rotating slots) covers L3 latency (~640cyc of FMA).
__global__ __launch_bounds__(256, 4) void lcn_conv(
    const float* __restrict__ x, const float* __restrict__ cw,
    float* __restrict__ P) {
  const int bid = blockIdx.x;        // 0..1599
  const int xcd = bid & 7;
  const int idx = bid >> 3;          // 0..199
  const int ws  = idx % 10;
  const int u   = xcd * 20 + idx / 10;   // 0..159 = (t, hs)
  const int hs  = u % 10;
  const int t   = u / 10;            // 0..15
  const int rq  = t >> 2;            // row quarter: rows rq*7 .. rq*7+6
  const int bg  = t & 3;             // 128-batch group
  const int s   = hs * 10 + ws;

  const int lane = threadIdx.x & 63;
  const int wid  = threadIdx.x >> 6;
  const int c4   = lane & 7;
  const int g    = lane >> 3;
  const int b0   = bg * 128 + wid * 32 + g * 4;

  __shared__ float4 wl[F_N * WQ];    // [f][r*7+c4], 490 float4 = 7.84 KB
  {
    const float4* wg = reinterpret_cast<const float4*>(cw);
    for (int i = (int)threadIdx.x; i < F_N * WQ; i += 256) {
      const int f = i / WQ, rem = i - f * WQ;
      wl[i] = wg[(f * SPAN + s) * 196 + rq * WQ + rem];
    }
  }
  __syncthreads();

  float acc[NB][F_N];
#pragma unroll
  for (int bi = 0; bi < NB; ++bi)
#pragma unroll
    for (int f = 0; f < F_N; ++f) acc[bi][f] = 0.f;

  const float* xb = x + (size_t)(hs * KK + rq * RQR) * HW + ws * KK + c4 * 4;

#define LOADROW(SLOT, ROW)                                                \
  _Pragma("unroll")                                                       \
  for (int bi = 0; bi < NB; ++bi)                                         \
    xv[SLOT][bi] = *reinterpret_cast<const float4*>(                      \
        xb + (size_t)(b0 + bi) * IMG + (size_t)(ROW) * HW);

#define COMPUTE(ROW, SLOT)                                                \
  {                                                                       \
    _Pragma("unroll")                                                     \
    for (int f = 0; f < F_N; ++f) {                                       \
      const float4 wv = wl[f * WQ + (ROW) * 7 + c4];                      \
      _Pragma("unroll")                                                   \
      for (int bi = 0; bi < NB; ++bi) {                                   \
        acc[bi][f] = fmaf(xv[SLOT][bi].x, wv.x, acc[bi][f]);              \
        acc[bi][f] = fmaf(xv[SLOT][bi].y, wv.y, acc[bi][f]);              \
        acc[bi][f] = fmaf(xv[SLOT][bi].z, wv.z, acc[bi][f]);              \
        acc[bi][f] = fmaf(xv[SLOT][bi].w, wv.w, acc[bi][f]);              \
      }                                                                   \
    }                                                                     \
  }

  if (c4 < 7) {
    float4 xv[3][NB];
    LOADROW(0, 0)
    LOADROW(1, 1)
#pragma unroll
    for (int r = 0; r < RQR; ++r) {
      const int slot = r % 3;
      if (r + 2 < RQR) { const int ns = (r + 2) % 3; LOADROW(ns, r + 2) }
      COMPUTE(r, slot)
    }
  }

  // sum over the 8-lane group's column quads (all lanes end with full sums)
#pragma unroll
  for (int bi = 0; bi < NB; ++bi)
#pragma unroll
    for (int f = 0; f < F_N; ++f) acc[bi][f] = red8(acc[bi][f]);

  // P[rq][f*100+s][b]: lane c4 writes f=c4 (float4 over bi), lanes 0,1 also f=8,9
  float* Pp = P + (size_t)rq * P_PLANE + (size_t)s * 512 + b0;
#pragma unroll
  for (int f = 0; f < F_N; ++f) {
    if (c4 == f || c4 == f - 8) {
      float4 v4 = make_float4(acc[0][f], acc[1][f], acc[2][f], acc[3][f]);
      *reinterpret_cast<float4*>(&Pp[(size_t)f * (SPAN * 512)]) = v4;
    }
  }
}

// Combine 4 rq quarters + bias + relu + decoder partials.
// grid 200 = dchunk(25) x bg(8); wave wid owns 10 d's; lane = b (coalesced).
__global__ __launch_bounds__(256) void lcn_dec(
    const float* __restrict__ P, const float* __restrict__ cb,
    const float* __restrict__ dw, float* __restrict__ yp) {
  const int bid    = blockIdx.x;
  const int dchunk = bid >> 3;     // 0..24
  const int bg     = bid & 7;
  const int lane   = threadIdx.x & 63;
  const int swid   = __builtin_amdgcn_readfirstlane((int)(threadIdx.x >> 6));
  const int d0     = dchunk * 40 + swid * 10;

  const float* Pb = P + (size_t)bg * 64 + lane;
  float acc[OUT_N];
#pragma unroll
  for (int o = 0; o < OUT_N; ++o) acc[o] = 0.f;

#pragma unroll
  for (int dd = 0; dd < 10; ++dd) {
    const int d = d0 + dd;                         // wave-uniform
    const float* pd = Pb + (size_t)d * 512;
    const float p = pd[0] + pd[P_PLANE] + pd[2 * (size_t)P_PLANE] + pd[3 * (size_t)P_PLANE];
    const float h = fmaxf(p + cb[d], 0.f);
#pragma unroll
    for (int o = 0; o < OUT_N; ++o)
      acc[o] = fmaf(h, dw[o * 1000 + d], acc[o]);  // wave-uniform -> s_load
  }
  float* ypp = yp + (size_t)(dchunk * 4 + swid) * 5120 + bg * 64 + lane;
#pragma unroll
  for (int o = 0; o < OUT_N; ++o) ypp[(size_t)o * 512] = acc[o];
}

// y[b][o] = db[o] + sum over 100 yp planes (coalesced per plane)
__global__ __launch_bounds__(256) void lcn_yred(
    const float* __restrict__ yp, const float* __restrict__ db,
    float* __restrict__ y) {
  const int idx = blockIdx.x * 256 + (int)threadIdx.x;  // 0..5119 = o*512+b
  const int o = idx >> 9;
  const int b = idx & 511;
  float a = db[o];
#pragma unroll 10
  for (int p = 0; p < 100; ++p) a += yp[(size_t)p * 5120 + idx];
  y[b * OUT_N + o] = a;
}

extern "C" void kernel_launch(void* const* d_in, const int* in_sizes, int n_in,
                              void* d_out, int out_size, void* d_ws, size_t ws_size,
                              hipStream_t stream) {
  const float* x  = (const float*)d_in[0];   // [512,1,280,280]
  const float* cw = (const float*)d_in[1];   // [1000,1,28,28]
  const float* cb = (const float*)d_in[2];   // [1000,1]
  const float* dw = (const float*)d_in[3];   // [10,1000]
  const float* db = (const float*)d_in[4];   // [10]
  float* y = (float*)d_out;                  // [512,10]

  float* P  = (float*)d_ws;                  // [4][1000][512] = 8.192 MB
  float* yp = P + 4 * (size_t)P_PLANE;       // [100][10][512] = 2.048 MB

  lcn_conv<<<dim3(1600), dim3(256), 0, stream>>>(x, cw, P);
  lcn_dec <<<dim3(200),  dim3(256), 0, stream>>>(P, cb, dw, yp);
  lcn_yred<<<dim3(20),   dim3(256), 0, stream>>>(yp, db, y);
}

// Round 7
// 45.160 us; speedup vs baseline: 6.8594x; 1.0089x over previous
//
#include <hip/hip_runtime.h>

// LCN: B=512, C=1, H=W=280, K=S=28, F=10, SPAN=100 (10x10), DEC_IN=1000, OUT=10
#define HW      280
#define IMG     78400        // 280*280
#define KK      28
#define F_N     10
#define SPAN    100
#define OUT_N   10
#define NB      4            // batches per thread
#define RQR     7            // patch rows per rq quarter
#define WQ      (RQR * 7)    // 49 float4 of w per filter per quarter
#define P_PLANE 512000       // 1000*512

// 8-lane-group reduction, pure DPP (VALU pipe, zero LDS ops):
// xor1 (quad_perm [1,0,3,2]), xor2 (quad_perm [2,3,0,1]); after those the
// value is quad-uniform, so ROW_HALF_MIRROR (lane i <-> 7-i within each 8)
// completes the 8-lane sum.
__device__ __forceinline__ float red8(float v) {
  v += __int_as_float(__builtin_amdgcn_mov_dpp(__float_as_int(v), 0xB1,  0xF, 0xF, true));
  v += __int_as_float(__builtin_amdgcn_mov_dpp(__float_as_int(v), 0x4E,  0xF, 0xF, true));
  v += __int_as_float(__builtin_amdgcn_mov_dpp(__float_as_int(v), 0x141, 0xF, 0xF, true));
  return v;
}

// Conv partials: grid 1600; decode keeps all 10 ws of one (t,hs) on one XCD.
// Block 256 = 4 waves x 8 groups x 8 lanes; each 8-lane group handles NB=4
// batches; lane c4 = one float4 column quad (c4==7 inert in conv, 28=7*4).
// w for (s, rq) staged in LDS (7.84 KB); each ds_read_b128 of w feeds 16 FMAs.
// ROUND 7: __launch_bounds__(256,3) (VGPR cap ~170 > ~130 demand) -- R5/R6's
// (256,4) capped at 128 < demand and almost certainly spilled in the unrolled
// inner loop (R4 variant measured 156 VGPRs). Depth-1 prefetch (2 slots).
__global__ __launch_bounds__(256, 3) void lcn_conv(
    const float* __restrict__ x, const float* __restrict__ cw,
    float* __restrict__ P) {
  const int bid = blockIdx.x;        // 0..1599
  const int xcd = bid & 7;
  const int idx = bid >> 3;          // 0..199
  const int ws  = idx % 10;
  const int u   = xcd * 20 + idx / 10;   // 0..159 = (t, hs)
  const int hs  = u % 10;
  const int t   = u / 10;            // 0..15
  const int rq  = t >> 2;            // row quarter: rows rq*7 .. rq*7+6
  const int bg  = t & 3;             // 128-batch group
  const int s   = hs * 10 + ws;

  const int lane = threadIdx.x & 63;
  const int wid  = threadIdx.x >> 6;
  const int c4   = lane & 7;
  const int g    = lane >> 3;
  const int b0   = bg * 128 + wid * 32 + g * 4;

  __shared__ float4 wl[F_N * WQ];    // [f][r*7+c4], 490 float4 = 7.84 KB
  {
    const float4* wg = reinterpret_cast<const float4*>(cw);
    for (int i = (int)threadIdx.x; i < F_N * WQ; i += 256) {
      const int f = i / WQ, rem = i - f * WQ;
      wl[i] = wg[(f * SPAN + s) * 196 + rq * WQ + rem];
    }
  }
  __syncthreads();

  float acc[NB][F_N];
#pragma unroll
  for (int bi = 0; bi < NB; ++bi)
#pragma unroll
    for (int f = 0; f < F_N; ++f) acc[bi][f] = 0.f;

  const float* xb = x + (size_t)(hs * KK + rq * RQR) * HW + ws * KK + c4 * 4;
  const float* xr0 = xb + (size_t)(b0 + 0) * IMG;
  const float* xr1 = xb + (size_t)(b0 + 1) * IMG;
  const float* xr2 = xb + (size_t)(b0 + 2) * IMG;
  const float* xr3 = xb + (size_t)(b0 + 3) * IMG;

#define LOADROW(SLOT, ROW)                                                   \
  xv[SLOT][0] = *reinterpret_cast<const float4*>(xr0 + (ROW) * HW);          \
  xv[SLOT][1] = *reinterpret_cast<const float4*>(xr1 + (ROW) * HW);          \
  xv[SLOT][2] = *reinterpret_cast<const float4*>(xr2 + (ROW) * HW);          \
  xv[SLOT][3] = *reinterpret_cast<const float4*>(xr3 + (ROW) * HW);

#define COMPUTE(ROW, SLOT)                                                \
  {                                                                       \
    _Pragma("unroll")                                                     \
    for (int f = 0; f < F_N; ++f) {                                       \
      const float4 wv = wl[f * WQ + (ROW) * 7 + c4];                      \
      _Pragma("unroll")                                                   \
      for (int bi = 0; bi < NB; ++bi) {                                   \
        acc[bi][f] = fmaf(xv[SLOT][bi].x, wv.x, acc[bi][f]);              \
        acc[bi][f] = fmaf(xv[SLOT][bi].y, wv.y, acc[bi][f]);              \
        acc[bi][f] = fmaf(xv[SLOT][bi].z, wv.z, acc[bi][f]);              \
        acc[bi][f] = fmaf(xv[SLOT][bi].w, wv.w, acc[bi][f]);              \
      }                                                                   \
    }                                                                     \
  }

  if (c4 < 7) {
    float4 xv[2][NB];
    LOADROW(0, 0)
#pragma unroll
    for (int r = 0; r < RQR; ++r) {
      if (r + 1 < RQR) { LOADROW((r + 1) & 1, r + 1) }
      COMPUTE(r, r & 1)
    }
  }

  // sum over the 8-lane group's column quads (all lanes end with full sums)
#pragma unroll
  for (int bi = 0; bi < NB; ++bi)
#pragma unroll
    for (int f = 0; f < F_N; ++f) acc[bi][f] = red8(acc[bi][f]);

  // P[rq][f*100+s][b]: lane c4 writes f=c4 (float4 over bi), lanes 0,1 also f=8,9
  float* Pp = P + (size_t)rq * P_PLANE + (size_t)s * 512 + b0;
#pragma unroll
  for (int f = 0; f < F_N; ++f) {
    if (c4 == f || c4 == f - 8) {
      float4 v4 = make_float4(acc[0][f], acc[1][f], acc[2][f], acc[3][f]);
      *reinterpret_cast<float4*>(&Pp[(size_t)f * (SPAN * 512)]) = v4;
    }
  }
}

// Combine 4 rq quarters + bias + relu + decoder partials.
// grid 200 = dchunk(25) x bg(8); wave wid owns 10 d's; lane = b (coalesced).
__global__ __launch_bounds__(256) void lcn_dec(
    const float* __restrict__ P, const float* __restrict__ cb,
    const float* __restrict__ dw, float* __restrict__ yp) {
  const int bid    = blockIdx.x;
  const int dchunk = bid >> 3;     // 0..24
  const int bg     = bid & 7;
  const int lane   = threadIdx.x & 63;
  const int swid   = __builtin_amdgcn_readfirstlane((int)(threadIdx.x >> 6));
  const int d0     = dchunk * 40 + swid * 10;

  const float* Pb = P + (size_t)bg * 64 + lane;
  float acc[OUT_N];
#pragma unroll
  for (int o = 0; o < OUT_N; ++o) acc[o] = 0.f;

#pragma unroll
  for (int dd = 0; dd < 10; ++dd) {
    const int d = d0 + dd;                         // wave-uniform
    const float* pd = Pb + (size_t)d * 512;
    const float p = pd[0] + pd[P_PLANE] + pd[2 * (size_t)P_PLANE] + pd[3 * (size_t)P_PLANE];
    const float h = fmaxf(p + cb[d], 0.f);
#pragma unroll
    for (int o = 0; o < OUT_N; ++o)
      acc[o] = fmaf(h, dw[o * 1000 + d], acc[o]);  // wave-uniform -> s_load
  }
  float* ypp = yp + (size_t)(dchunk * 4 + swid) * 5120 + bg * 64 + lane;
#pragma unroll
  for (int o = 0; o < OUT_N; ++o) ypp[(size_t)o * 512] = acc[o];
}

// y[b][o] = db[o] + sum over 100 yp planes (coalesced per plane)
__global__ __launch_bounds__(256) void lcn_yred(
    const float* __restrict__ yp, const float* __restrict__ db,
    float* __restrict__ y) {
  const int idx = blockIdx.x * 256 + (int)threadIdx.x;  // 0..5119 = o*512+b
  const int o = idx >> 9;
  const int b = idx & 511;
  float a = db[o];
#pragma unroll 10
  for (int p = 0; p < 100; ++p) a += yp[(size_t)p * 5120 + idx];
  y[b * OUT_N + o] = a;
}

extern "C" void kernel_launch(void* const* d_in, const int* in_sizes, int n_in,
                              void* d_out, int out_size, void* d_ws, size_t ws_size,
                              hipStream_t stream) {
  const float* x  = (const float*)d_in[0];   // [512,1,280,280]
  const float* cw = (const float*)d_in[1];   // [1000,1,28,28]
  const float* cb = (const float*)d_in[2];   // [1000,1]
  const float* dw = (const float*)d_in[3];   // [10,1000]
  const float* db = (const float*)d_in[4];   // [10]
  float* y = (float*)d_out;                  // [512,10]

  float* P  = (float*)d_ws;                  // [4][1000][512] = 8.192 MB
  float* yp = P + 4 * (size_t)P_PLANE;       // [100][10][512] = 2.048 MB

  lcn_conv<<<dim3(1600), dim3(256), 0, stream>>>(x, cw, P);
  lcn_dec <<<dim3(200),  dim3(256), 0, stream>>>(P, cb, dw, yp);
  lcn_yred<<<dim3(20),   dim3(256), 0, stream>>>(yp, db, y);
}